// Round 10
// baseline (219.633 us; speedup 1.0000x reference)
//
#include <hip/hip_runtime.h>

typedef __bf16 bf16x8 __attribute__((ext_vector_type(8)));
typedef __bf16 bf16x4 __attribute__((ext_vector_type(4)));
typedef float  f32x4  __attribute__((ext_vector_type(4)));

// 0.125 (softmax scale) * log2(e), folded into exp2
#define CS 0.18033688011112042f

__device__ __forceinline__ float fast_exp2(float x) {
    return __builtin_amdgcn_exp2f(x);
}

// ---------------------------------------------------------------------------
// MFMA wrapper: gfx950 v_mfma_f32_16x16x32_bf16
//   A-frag: A[m=lane&15][k=8*(lane>>4)+j]   (8 bf16)
//   B-frag: B[k=8*(lane>>4)+j][n=lane&15]   (8 bf16)  == W[n][k] for gemm_bt
//   C/D   : D[row=4*(lane>>4)+reg][col=lane&15]
// ---------------------------------------------------------------------------
__device__ __forceinline__ f32x4 MFMA(bf16x8 a, bf16x8 b, f32x4 c) {
    return __builtin_amdgcn_mfma_f32_16x16x32_bf16(a, b, c, 0, 0, 0);
}

// async global->LDS 16B copy: LDS dest must be wave-uniform base + lane*16
__device__ __forceinline__ void ldsgcpy16(__bf16* lds, const __bf16* g) {
    __builtin_amdgcn_global_load_lds(
        (const __attribute__((address_space(1))) unsigned int*)g,
        (__attribute__((address_space(3))) unsigned int*)lds, 16, 0, 0);
}

// ---------------------------------------------------------------------------
// gemm_bt core: C[m0:m0+128, n0:n0+BN] = A[m0:,:1024] * W[n0:,:1024]^T + bias
// AF32/BF32: operand is fp32 in global; convert to bf16 during VALU staging
// (fuses the old cvt5 kernel). bf16 operands stage via global_load_lds DMA
// with the swizzle folded into the global source chunk. Both paths produce
// identical LDS layout: lds[row][cc] holds global chunk cc^(row&7).
// ---------------------------------------------------------------------------
template <typename OutT, int BN, bool AF32, bool BF32>
__device__ __forceinline__ void gemm_core(const void* __restrict__ Araw,
                                          const void* __restrict__ Wraw,
                                          const float* __restrict__ bias,
                                          OutT* __restrict__ C,
                                          int m0, int n0, bool vtrans)
{
    constexpr int NJ = BN / 32;
    __shared__ __bf16 As[128 * 64];
    __shared__ __bf16 Bs[BN * 64];

    const int tid  = threadIdx.x;
    const int lane = tid & 63;
    const int w    = tid >> 6;      // wave 0..3
    const int wm   = w & 1;         // 2x2 wave grid
    const int wn   = w >> 1;
    const int s    = lane & 15;
    const int q    = lane >> 4;

    f32x4 acc[4][NJ];
#pragma unroll
    for (int i = 0; i < 4; i++)
#pragma unroll
        for (int j = 0; j < NJ; j++)
#pragma unroll
            for (int r = 0; r < 4; r++) acc[i][j][r] = 0.0f;

    for (int k0 = 0; k0 < 1024; k0 += 64) {
        __syncthreads();   // previous iter's LDS reads done
#pragma unroll
        for (int t = 0; t < 4; t++) {
            int c   = tid + 256 * t;    // 0..1023 vec8 chunks
            int row = c >> 3;
            int cc  = c & 7;
            if (AF32) {
                const float* Af = (const float*)Araw;
                const float* g  = Af + (size_t)(m0 + row) * 1024 + k0 + cc * 8;
                float4 v0 = *(const float4*)g;
                float4 v1 = *(const float4*)(g + 4);
                bf16x8 o;
                o[0] = (__bf16)v0.x; o[1] = (__bf16)v0.y;
                o[2] = (__bf16)v0.z; o[3] = (__bf16)v0.w;
                o[4] = (__bf16)v1.x; o[5] = (__bf16)v1.y;
                o[6] = (__bf16)v1.z; o[7] = (__bf16)v1.w;
                *(bf16x8*)&As[row * 64 + ((cc ^ (row & 7)) << 3)] = o;
            } else {
                const __bf16* Ab = (const __bf16*)Araw;
                int ccp = cc ^ (row & 7);
                ldsgcpy16(&As[c * 8], Ab + (size_t)(m0 + row) * 1024 + k0 + ccp * 8);
            }
        }
#pragma unroll
        for (int t = 0; t < BN / 32; t++) {
            int c   = tid + 256 * t;    // 0..BN*8-1
            int row = c >> 3;
            int cc  = c & 7;
            if (BF32) {
                const float* Wf = (const float*)Wraw;
                const float* g  = Wf + (size_t)(n0 + row) * 1024 + k0 + cc * 8;
                float4 v0 = *(const float4*)g;
                float4 v1 = *(const float4*)(g + 4);
                bf16x8 o;
                o[0] = (__bf16)v0.x; o[1] = (__bf16)v0.y;
                o[2] = (__bf16)v0.z; o[3] = (__bf16)v0.w;
                o[4] = (__bf16)v1.x; o[5] = (__bf16)v1.y;
                o[6] = (__bf16)v1.z; o[7] = (__bf16)v1.w;
                *(bf16x8*)&Bs[row * 64 + ((cc ^ (row & 7)) << 3)] = o;
            } else {
                const __bf16* Wb = (const __bf16*)Wraw;
                int ccp = cc ^ (row & 7);
                ldsgcpy16(&Bs[c * 8], Wb + (size_t)(n0 + row) * 1024 + k0 + ccp * 8);
            }
        }
        __syncthreads();   // drains vmcnt (DMA) + lgkmcnt (ds_write) before reads

#pragma unroll
        for (int kk = 0; kk < 2; kk++) {    // two k-steps of 32
            bf16x8 af[4], bf[NJ];
#pragma unroll
            for (int i = 0; i < 4; i++) {
                int row = wm * 64 + i * 16 + s;
                int idx = row * 64 + ((((kk << 2) + q) ^ (row & 7)) << 3);
                af[i] = *(const bf16x8*)&As[idx];
            }
#pragma unroll
            for (int j = 0; j < NJ; j++) {
                int row = wn * (BN / 2) + j * 16 + s;
                int idx = row * 64 + ((((kk << 2) + q) ^ (row & 7)) << 3);
                bf[j] = *(const bf16x8*)&Bs[idx];
            }
#pragma unroll
            for (int i = 0; i < 4; i++)
#pragma unroll
                for (int j = 0; j < NJ; j++)
                    acc[i][j] = MFMA(af[i], bf[j], acc[i][j]);
        }
    }

    if (vtrans) {
        // transposed per-head write: Vt[((b*16+h)*64 + d)*2048 + srow]
        __bf16* Vt = (__bf16*)C;
#pragma unroll
        for (int j = 0; j < NJ; j++) {
            int col = n0 + wn * (BN / 2) + j * 16 + s;
            int h   = col >> 6;
            int d   = col & 63;
            float bv = bias[col];
#pragma unroll
            for (int i = 0; i < 4; i++) {
                int rowb = m0 + wm * 64 + i * 16 + q * 4;
                int b    = rowb >> 11;
                int srow = rowb & 2047;
                bf16x4 pk;
#pragma unroll
                for (int r = 0; r < 4; r++) pk[r] = (__bf16)(acc[i][j][r] + bv);
                *(bf16x4*)&Vt[(size_t)((b * 16 + h) * 64 + d) * 2048 + srow] = pk;
            }
        }
    } else {
#pragma unroll
        for (int j = 0; j < NJ; j++) {
            int col = n0 + wn * (BN / 2) + j * 16 + s;
            float bv = bias[col];
#pragma unroll
            for (int i = 0; i < 4; i++) {
                int rowb = m0 + wm * 64 + i * 16 + q * 4;
#pragma unroll
                for (int r = 0; r < 4; r++) {
                    C[(size_t)(rowb + r) * 1024 + col] = (OutT)(acc[i][j][r] + bv);
                }
            }
        }
    }
}

// Fused cvt+QKV projection: grid = 32 m-tiles x 24 n-tiles (8 per matrix)
__global__ __launch_bounds__(256) void gemm_qkv_kernel(
    const float* __restrict__ X,
    const float* __restrict__ Wq, const float* __restrict__ bq,
    const float* __restrict__ Wk, const float* __restrict__ bk,
    const float* __restrict__ Wv, const float* __restrict__ bv,
    __bf16* __restrict__ Q, __bf16* __restrict__ K, __bf16* __restrict__ Vt)
{
    int mt = blockIdx.x / 24;
    int nt = blockIdx.x % 24;
    int which = nt >> 3;
    const float* W    = (which == 0) ? Wq : (which == 1) ? Wk : Wv;
    const float* bias = (which == 0) ? bq : (which == 1) ? bk : bv;
    __bf16*      Out  = (which == 0) ? Q  : (which == 1) ? K  : Vt;
    gemm_core<__bf16, 128, true, true>(X, W, bias, Out,
                                       mt * 128, (nt & 7) * 128, which == 2);
}

// O-proj (fused Wo cvt): 128x64 tiles -> 512 blocks
__global__ __launch_bounds__(256) void gemm_o_kernel(
    const __bf16* __restrict__ Ain, const float* __restrict__ Wo,
    const float* __restrict__ bo, float* __restrict__ Out)
{
    int mt = blockIdx.x >> 4;
    int nt = blockIdx.x & 15;
    gemm_core<float, 64, false, true>(Ain, Wo, bo, Out, mt * 128, nt * 64, false);
}

// ---------------------------------------------------------------------------
// Flash attention (r7-proven): grid = 32 bh * 16 q-tiles(128 rows). 4 waves,
// wave owns 32 q-rows. K staged row-permuted (rho(krow)=(krow&7)*16+(krow>>3))
// so each lane's softmax outputs are 8 contiguous P cols -> packed b128 write.
// Register prefetch pipeline for K/Vt staging. LDS 64KB -> 2 blocks/CU.
// ---------------------------------------------------------------------------
__global__ __launch_bounds__(256, 2) void attn_kernel(
    const __bf16* __restrict__ Q, const __bf16* __restrict__ K,
    const __bf16* __restrict__ Vt, __bf16* __restrict__ O)
{
    __shared__ __bf16 k_lds[128 * 64];     // [rho(krow)][d]  16B-block xor swizzle
    __shared__ __bf16 vt_lds[64 * 128];    // [d][krow]       16B-block xor swizzle
    __shared__ __bf16 p_lds[4 * 32 * 128]; // per-wave [32 rows][128 cols]

    const int bh = blockIdx.x >> 4;       // 0..31
    const int qt = blockIdx.x & 15;       // q-tile (128 rows)
    const int b  = bh >> 4;
    const int h  = bh & 15;

    const int tid  = threadIdx.x;
    const int lane = tid & 63;
    const int w    = tid >> 6;
    const int s    = lane & 15;
    const int q    = lane >> 4;

    // preload Q A-frags for this wave's 32 rows
    bf16x8 aq[2][2];
#pragma unroll
    for (int i = 0; i < 2; i++)
#pragma unroll
        for (int kd = 0; kd < 2; kd++) {
            int row = qt * 128 + w * 32 + i * 16 + s;
            aq[i][kd] = *(const bf16x8*)(Q + (size_t)(b * 2048 + row) * 1024 +
                                         h * 64 + kd * 32 + q * 8);
        }

    f32x4 acc_o[2][4];
    float lst[2][4];
#pragma unroll
    for (int i = 0; i < 2; i++)
#pragma unroll
        for (int r = 0; r < 4; r++) {
            lst[i][r] = 0.0f;
#pragma unroll
            for (int jd = 0; jd < 4; jd++) acc_o[i][jd][r] = 0.0f;
        }

    const int pbase = w * 32 * 128;

    // register prefetch buffers (chunk staging: 4x16B K + 4x16B Vt per thread)
    bf16x8 kpre[4], vpre[4];
#pragma unroll
    for (int t = 0; t < 4; t++) {
        int c = tid + 256 * t;
        int krow = c >> 3, cc = c & 7;
        kpre[t] = *(const bf16x8*)(K + (size_t)(b * 2048 + krow) * 1024 +
                                   h * 64 + cc * 8);
        int d = c >> 4, ck = c & 15;
        vpre[t] = *(const bf16x8*)(Vt + (size_t)(bh * 64 + d) * 2048 + ck * 8);
    }

    for (int kc = 0; kc < 16; kc++) {
        __syncthreads();   // all waves done reading prev chunk's LDS
#pragma unroll
        for (int t = 0; t < 4; t++) {
            int c = tid + 256 * t;
            int krow = c >> 3, cc = c & 7;
            int rho  = ((krow & 7) << 4) | (krow >> 3);   // row permutation
            *(bf16x8*)&k_lds[rho * 64 + ((cc ^ (rho & 7)) << 3)] = kpre[t];
            int d = c >> 4, ck = c & 15;
            *(bf16x8*)&vt_lds[(d * 16 + (ck ^ (d & 7))) << 3] = vpre[t];
        }
        __syncthreads();

        // prefetch next chunk into registers (wraps at end; harmless)
        int kb2 = ((kc + 1) & 15) * 128;
#pragma unroll
        for (int t = 0; t < 4; t++) {
            int c = tid + 256 * t;
            int krow = c >> 3, cc = c & 7;
            kpre[t] = *(const bf16x8*)(K + (size_t)(b * 2048 + kb2 + krow) * 1024 +
                                       h * 64 + cc * 8);
            int d = c >> 4, ck = c & 15;
            vpre[t] = *(const bf16x8*)(Vt + (size_t)(bh * 64 + d) * 2048 + kb2 + ck * 8);
        }

        // ---- S = Q K^T; col n=s of block j holds K-row s*8+j ----
        f32x4 sc[2][8];
#pragma unroll
        for (int i = 0; i < 2; i++)
#pragma unroll
            for (int j = 0; j < 8; j++)
#pragma unroll
                for (int r = 0; r < 4; r++) sc[i][j][r] = 0.0f;
#pragma unroll
        for (int kd = 0; kd < 2; kd++) {
#pragma unroll
            for (int j = 0; j < 8; j++) {
                int row = j * 16 + s;
                int idx = row * 64 + ((((kd << 2) + q) ^ (row & 7)) << 3);
                bf16x8 bf = *(const bf16x8*)&k_lds[idx];
                sc[0][j] = MFMA(aq[0][kd], bf, sc[0][j]);
                sc[1][j] = MFMA(aq[1][kd], bf, sc[1][j]);
            }
        }

        // ---- max-free softmax + PACKED P write (cols s*8..s*8+7) ----
#pragma unroll
        for (int i = 0; i < 2; i++)
#pragma unroll
            for (int r = 0; r < 4; r++) {
                int prow = i * 16 + q * 4 + r;
                bf16x8 pk;
                float rsum = 0.0f;
#pragma unroll
                for (int j = 0; j < 8; j++) {
                    float p = fast_exp2(sc[i][j][r] * CS);
                    rsum += p;
                    pk[j] = (__bf16)p;
                }
                lst[i][r] += rsum;
                int chunkp = s ^ (prow & 15);
                *(bf16x8*)&p_lds[pbase + prow * 128 + (chunkp << 3)] = pk;
            }

        // ---- O += P V (p rows wave-private; in-wave ordering suffices) ----
#pragma unroll
        for (int kk = 0; kk < 4; kk++) {
            bf16x8 ap[2];
#pragma unroll
            for (int i = 0; i < 2; i++) {
                int prow = i * 16 + s;             // prow & 15 == s
                int chunkr = ((kk << 2) + q) ^ s;
                ap[i] = *(const bf16x8*)&p_lds[pbase + prow * 128 + (chunkr << 3)];
            }
#pragma unroll
            for (int jd = 0; jd < 4; jd++) {
                int d    = jd * 16 + s;
                int vidx = (d * 16 + (((kk << 2) + q) ^ (d & 7))) << 3;
                bf16x8 bv = *(const bf16x8*)&vt_lds[vidx];
                acc_o[0][jd] = MFMA(ap[0], bv, acc_o[0][jd]);
                acc_o[1][jd] = MFMA(ap[1], bv, acc_o[1][jd]);
            }
        }
    }

    // ---- deferred l reduction over the 16 s-lanes (q preserved by xor<16) ----
#pragma unroll
    for (int i = 0; i < 2; i++)
#pragma unroll
        for (int r = 0; r < 4; r++) {
#pragma unroll
            for (int off = 1; off < 16; off <<= 1)
                lst[i][r] += __shfl_xor(lst[i][r], off);
        }

    // ---- epilogue: O / l, merge heads ----
#pragma unroll
    for (int i = 0; i < 2; i++)
#pragma unroll
        for (int jd = 0; jd < 4; jd++)
#pragma unroll
            for (int r = 0; r < 4; r++) {
                int row = qt * 128 + w * 32 + i * 16 + q * 4 + r;
                int col = h * 64 + jd * 16 + s;
                float v = acc_o[i][jd][r] / lst[i][r];
                O[(size_t)(b * 2048 + row) * 1024 + col] = (__bf16)v;
            }
}

// ---------------------------------------------------------------------------
extern "C" void kernel_launch(void* const* d_in, const int* in_sizes, int n_in,
                              void* d_out, int out_size, void* d_ws, size_t ws_size,
                              hipStream_t stream)
{
    const float* hs = (const float*)d_in[0];
    const float* qw = (const float*)d_in[1];
    const float* qb = (const float*)d_in[2];
    const float* kw = (const float*)d_in[3];
    const float* kb = (const float*)d_in[4];
    const float* vw = (const float*)d_in[5];
    const float* vb = (const float*)d_in[6];
    const float* ow = (const float*)d_in[7];
    const float* ob = (const float*)d_in[8];
    float* out = (float*)d_out;

    char* ws = (char*)d_ws;
    const size_t MB = (size_t)1024 * 1024;
    __bf16* Qb  = (__bf16*)(ws);             //  8 MB
    __bf16* Kb  = (__bf16*)(ws +  8 * MB);   //  8 MB
    __bf16* Vtb = (__bf16*)(ws + 16 * MB);   //  8 MB  [32 bh][64 d][2048 s]
    __bf16* Ab  = (__bf16*)(ws + 24 * MB);   //  8 MB

    gemm_qkv_kernel<<<dim3(768), dim3(256), 0, stream>>>(hs, qw, qb, kw, kb, vw, vb,
                                                         Qb, Kb, Vtb);
    attn_kernel<<<dim3(512), dim3(256), 0, stream>>>(Qb, Kb, Vtb, Ab);
    gemm_o_kernel<<<dim3(512), dim3(256), 0, stream>>>(Ab, ow, ob, out);
}

// Round 11
// 188.441 us; speedup vs baseline: 1.1655x; 1.1655x over previous
//
#include <hip/hip_runtime.h>

typedef __bf16 bf16x8 __attribute__((ext_vector_type(8)));
typedef __bf16 bf16x4 __attribute__((ext_vector_type(4)));
typedef float  f32x4  __attribute__((ext_vector_type(4)));

// 0.125 (softmax scale) * log2(e), folded into exp2
#define CS 0.18033688011112042f

__device__ __forceinline__ float fast_exp2(float x) {
    return __builtin_amdgcn_exp2f(x);
}

// ---------------------------------------------------------------------------
// MFMA wrapper: gfx950 v_mfma_f32_16x16x32_bf16
//   A-frag: A[m=lane&15][k=8*(lane>>4)+j]   (8 bf16)
//   B-frag: B[k=8*(lane>>4)+j][n=lane&15]   (8 bf16)  == W[n][k] for gemm_bt
//   C/D   : D[row=4*(lane>>4)+reg][col=lane&15]
// ---------------------------------------------------------------------------
__device__ __forceinline__ f32x4 MFMA(bf16x8 a, bf16x8 b, f32x4 c) {
    return __builtin_amdgcn_mfma_f32_16x16x32_bf16(a, b, c, 0, 0, 0);
}

// fp32 -> bf16 convert, all 5 tensors in one launch.
__global__ __launch_bounds__(256) void cvt5_kernel(
    const float* __restrict__ s0, const float* __restrict__ s1,
    const float* __restrict__ s2, const float* __restrict__ s3,
    const float* __restrict__ s4,
    __bf16* __restrict__ d0, __bf16* __restrict__ d1, __bf16* __restrict__ d2,
    __bf16* __restrict__ d3, __bf16* __restrict__ d4)
{
    int blk = blockIdx.x;
    const float* src; __bf16* dst; int base;
    if (blk < 4096)      { src = s0; dst = d0; base = blk; }
    else if (blk < 5120) { src = s1; dst = d1; base = blk - 4096; }
    else if (blk < 6144) { src = s2; dst = d2; base = blk - 5120; }
    else if (blk < 7168) { src = s3; dst = d3; base = blk - 6144; }
    else                 { src = s4; dst = d4; base = blk - 7168; }
    int i = base * 1024 + threadIdx.x * 4;
    float4 v = *(const float4*)(src + i);
    bf16x4 o;
    o[0] = (__bf16)v.x; o[1] = (__bf16)v.y; o[2] = (__bf16)v.z; o[3] = (__bf16)v.w;
    *(bf16x4*)(dst + i) = o;
}

// ---------------------------------------------------------------------------
// gemm_bt core: C[m0:m0+128, n0:n0+BN] = A[m0:,:1024] * W[n0:,:1024]^T + bias
// Register-prefetch staging: tile k+1 is loaded into VGPRs right after the
// compute barrier, overlapping global latency with the MFMA phase (same
// pipeline that won in the attention kernel, r5).
// ---------------------------------------------------------------------------
template <typename OutT, int BN>
__device__ __forceinline__ void gemm_core(const __bf16* __restrict__ A,
                                          const __bf16* __restrict__ W,
                                          const float* __restrict__ bias,
                                          OutT* __restrict__ C,
                                          int m0, int n0, bool vtrans)
{
    constexpr int NJ = BN / 32;
    __shared__ __bf16 As[128 * 64];
    __shared__ __bf16 Bs[BN * 64];

    const int tid  = threadIdx.x;
    const int lane = tid & 63;
    const int w    = tid >> 6;      // wave 0..3
    const int wm   = w & 1;         // 2x2 wave grid
    const int wn   = w >> 1;
    const int s    = lane & 15;
    const int q    = lane >> 4;

    f32x4 acc[4][NJ];
#pragma unroll
    for (int i = 0; i < 4; i++)
#pragma unroll
        for (int j = 0; j < NJ; j++)
#pragma unroll
            for (int r = 0; r < 4; r++) acc[i][j][r] = 0.0f;

    // prefetch registers for the k-tile being staged next
    bf16x8 apre[4], bpre[NJ];
#pragma unroll
    for (int t = 0; t < 4; t++) {
        int c = tid + 256 * t, row = c >> 3, cc = c & 7;
        apre[t] = *(const bf16x8*)(A + (size_t)(m0 + row) * 1024 + cc * 8);
    }
#pragma unroll
    for (int t = 0; t < NJ; t++) {
        int c = tid + 256 * t, row = c >> 3, cc = c & 7;
        bpre[t] = *(const bf16x8*)(W + (size_t)(n0 + row) * 1024 + cc * 8);
    }

    for (int k0 = 0; k0 < 1024; k0 += 64) {
        __syncthreads();   // previous iter's LDS reads done
#pragma unroll
        for (int t = 0; t < 4; t++) {
            int c = tid + 256 * t, row = c >> 3, cc = c & 7;
            *(bf16x8*)&As[row * 64 + ((cc ^ (row & 7)) << 3)] = apre[t];
        }
#pragma unroll
        for (int t = 0; t < NJ; t++) {
            int c = tid + 256 * t, row = c >> 3, cc = c & 7;
            *(bf16x8*)&Bs[row * 64 + ((cc ^ (row & 7)) << 3)] = bpre[t];
        }
        __syncthreads();

        if (k0 < 1024 - 64) {    // prefetch next tile (overlaps MFMA below)
            int kn = k0 + 64;
#pragma unroll
            for (int t = 0; t < 4; t++) {
                int c = tid + 256 * t, row = c >> 3, cc = c & 7;
                apre[t] = *(const bf16x8*)(A + (size_t)(m0 + row) * 1024 + kn + cc * 8);
            }
#pragma unroll
            for (int t = 0; t < NJ; t++) {
                int c = tid + 256 * t, row = c >> 3, cc = c & 7;
                bpre[t] = *(const bf16x8*)(W + (size_t)(n0 + row) * 1024 + kn + cc * 8);
            }
        }

#pragma unroll
        for (int kk = 0; kk < 2; kk++) {    // two k-steps of 32
            bf16x8 af[4], bf[NJ];
#pragma unroll
            for (int i = 0; i < 4; i++) {
                int row = wm * 64 + i * 16 + s;
                int idx = row * 64 + ((((kk << 2) + q) ^ (row & 7)) << 3);
                af[i] = *(const bf16x8*)&As[idx];
            }
#pragma unroll
            for (int j = 0; j < NJ; j++) {
                int row = wn * (BN / 2) + j * 16 + s;
                int idx = row * 64 + ((((kk << 2) + q) ^ (row & 7)) << 3);
                bf[j] = *(const bf16x8*)&Bs[idx];
            }
#pragma unroll
            for (int i = 0; i < 4; i++)
#pragma unroll
                for (int j = 0; j < NJ; j++)
                    acc[i][j] = MFMA(af[i], bf[j], acc[i][j]);
        }
    }

    if (vtrans) {
        // transposed per-head write: Vt[((b*16+h)*64 + d)*2048 + srow]
        __bf16* Vt = (__bf16*)C;
#pragma unroll
        for (int j = 0; j < NJ; j++) {
            int col = n0 + wn * (BN / 2) + j * 16 + s;
            int h   = col >> 6;
            int d   = col & 63;
            float bv = bias[col];
#pragma unroll
            for (int i = 0; i < 4; i++) {
                int rowb = m0 + wm * 64 + i * 16 + q * 4;
                int b    = rowb >> 11;
                int srow = rowb & 2047;
                bf16x4 pk;
#pragma unroll
                for (int r = 0; r < 4; r++) pk[r] = (__bf16)(acc[i][j][r] + bv);
                *(bf16x4*)&Vt[(size_t)((b * 16 + h) * 64 + d) * 2048 + srow] = pk;
            }
        }
    } else {
#pragma unroll
        for (int j = 0; j < NJ; j++) {
            int col = n0 + wn * (BN / 2) + j * 16 + s;
            float bv = bias[col];
#pragma unroll
            for (int i = 0; i < 4; i++) {
                int rowb = m0 + wm * 64 + i * 16 + q * 4;
#pragma unroll
                for (int r = 0; r < 4; r++) {
                    C[(size_t)(rowb + r) * 1024 + col] = (OutT)(acc[i][j][r] + bv);
                }
            }
        }
    }
}

// Fused QKV projection. Block mapping: blockIdx = ntot*32 + mt, so XCD
// (= blockIdx % 8, round-robin) = mt % 8 -> all 24 blocks sharing an X
// m-tile land on one XCD and reuse its L2 copy of X.
__global__ __launch_bounds__(256) void gemm_qkv_kernel(
    const __bf16* __restrict__ X,
    const __bf16* __restrict__ Wq, const float* __restrict__ bq,
    const __bf16* __restrict__ Wk, const float* __restrict__ bk,
    const __bf16* __restrict__ Wv, const float* __restrict__ bv,
    __bf16* __restrict__ Q, __bf16* __restrict__ K, __bf16* __restrict__ Vt)
{
    int mt   = blockIdx.x & 31;
    int ntot = blockIdx.x >> 5;    // 0..23
    int which = ntot >> 3;
    const __bf16* W    = (which == 0) ? Wq : (which == 1) ? Wk : Wv;
    const float*  bias = (which == 0) ? bq : (which == 1) ? bk : bv;
    __bf16*       Out  = (which == 0) ? Q  : (which == 1) ? K  : Vt;
    gemm_core<__bf16, 128>(X, W, bias, Out, mt * 128, (ntot & 7) * 128, which == 2);
}

// O-proj: 128x64 tiles -> 512 blocks; same XCD-aware mapping on mt.
__global__ __launch_bounds__(256) void gemm_o_kernel(
    const __bf16* __restrict__ Ain, const __bf16* __restrict__ Wo,
    const float* __restrict__ bo, float* __restrict__ Out)
{
    int mt = blockIdx.x & 31;
    int nt = blockIdx.x >> 5;      // 0..15
    gemm_core<float, 64>(Ain, Wo, bo, Out, mt * 128, nt * 64, false);
}

// ---------------------------------------------------------------------------
// Flash attention (r7-proven, best measured 57.6us): grid = 32 bh * 16
// q-tiles(128 rows). 4 waves, wave owns 32 q-rows. K staged row-permuted
// (rho(krow)=(krow&7)*16+(krow>>3)) so each lane's softmax outputs are 8
// contiguous P cols -> packed b128 write. Register prefetch for K/Vt.
// LDS 64KB -> 2 blocks/CU.
// ---------------------------------------------------------------------------
__global__ __launch_bounds__(256, 2) void attn_kernel(
    const __bf16* __restrict__ Q, const __bf16* __restrict__ K,
    const __bf16* __restrict__ Vt, __bf16* __restrict__ O)
{
    __shared__ __bf16 k_lds[128 * 64];     // [rho(krow)][d]  16B-block xor swizzle
    __shared__ __bf16 vt_lds[64 * 128];    // [d][krow]       16B-block xor swizzle
    __shared__ __bf16 p_lds[4 * 32 * 128]; // per-wave [32 rows][128 cols]

    const int bh = blockIdx.x >> 4;       // 0..31
    const int qt = blockIdx.x & 15;       // q-tile (128 rows)
    const int b  = bh >> 4;
    const int h  = bh & 15;

    const int tid  = threadIdx.x;
    const int lane = tid & 63;
    const int w    = tid >> 6;
    const int s    = lane & 15;
    const int q    = lane >> 4;

    // preload Q A-frags for this wave's 32 rows
    bf16x8 aq[2][2];
#pragma unroll
    for (int i = 0; i < 2; i++)
#pragma unroll
        for (int kd = 0; kd < 2; kd++) {
            int row = qt * 128 + w * 32 + i * 16 + s;
            aq[i][kd] = *(const bf16x8*)(Q + (size_t)(b * 2048 + row) * 1024 +
                                         h * 64 + kd * 32 + q * 8);
        }

    f32x4 acc_o[2][4];
    float lst[2][4];
#pragma unroll
    for (int i = 0; i < 2; i++)
#pragma unroll
        for (int r = 0; r < 4; r++) {
            lst[i][r] = 0.0f;
#pragma unroll
            for (int jd = 0; jd < 4; jd++) acc_o[i][jd][r] = 0.0f;
        }

    const int pbase = w * 32 * 128;

    // register prefetch buffers (chunk staging: 4x16B K + 4x16B Vt per thread)
    bf16x8 kpre[4], vpre[4];
#pragma unroll
    for (int t = 0; t < 4; t++) {
        int c = tid + 256 * t;
        int krow = c >> 3, cc = c & 7;
        kpre[t] = *(const bf16x8*)(K + (size_t)(b * 2048 + krow) * 1024 +
                                   h * 64 + cc * 8);
        int d = c >> 4, ck = c & 15;
        vpre[t] = *(const bf16x8*)(Vt + (size_t)(bh * 64 + d) * 2048 + ck * 8);
    }

    for (int kc = 0; kc < 16; kc++) {
        __syncthreads();   // all waves done reading prev chunk's LDS
#pragma unroll
        for (int t = 0; t < 4; t++) {
            int c = tid + 256 * t;
            int krow = c >> 3, cc = c & 7;
            int rho  = ((krow & 7) << 4) | (krow >> 3);   // row permutation
            *(bf16x8*)&k_lds[rho * 64 + ((cc ^ (rho & 7)) << 3)] = kpre[t];
            int d = c >> 4, ck = c & 15;
            *(bf16x8*)&vt_lds[(d * 16 + (ck ^ (d & 7))) << 3] = vpre[t];
        }
        __syncthreads();

        // prefetch next chunk into registers (wraps at end; harmless)
        int kb2 = ((kc + 1) & 15) * 128;
#pragma unroll
        for (int t = 0; t < 4; t++) {
            int c = tid + 256 * t;
            int krow = c >> 3, cc = c & 7;
            kpre[t] = *(const bf16x8*)(K + (size_t)(b * 2048 + kb2 + krow) * 1024 +
                                       h * 64 + cc * 8);
            int d = c >> 4, ck = c & 15;
            vpre[t] = *(const bf16x8*)(Vt + (size_t)(bh * 64 + d) * 2048 + kb2 + ck * 8);
        }

        // ---- S = Q K^T; col n=s of block j holds K-row s*8+j ----
        f32x4 sc[2][8];
#pragma unroll
        for (int i = 0; i < 2; i++)
#pragma unroll
            for (int j = 0; j < 8; j++)
#pragma unroll
                for (int r = 0; r < 4; r++) sc[i][j][r] = 0.0f;
#pragma unroll
        for (int kd = 0; kd < 2; kd++) {
#pragma unroll
            for (int j = 0; j < 8; j++) {
                int row = j * 16 + s;
                int idx = row * 64 + ((((kd << 2) + q) ^ (row & 7)) << 3);
                bf16x8 bf = *(const bf16x8*)&k_lds[idx];
                sc[0][j] = MFMA(aq[0][kd], bf, sc[0][j]);
                sc[1][j] = MFMA(aq[1][kd], bf, sc[1][j]);
            }
        }

        // ---- max-free softmax + PACKED P write (cols s*8..s*8+7) ----
#pragma unroll
        for (int i = 0; i < 2; i++)
#pragma unroll
            for (int r = 0; r < 4; r++) {
                int prow = i * 16 + q * 4 + r;
                bf16x8 pk;
                float rsum = 0.0f;
#pragma unroll
                for (int j = 0; j < 8; j++) {
                    float p = fast_exp2(sc[i][j][r] * CS);
                    rsum += p;
                    pk[j] = (__bf16)p;
                }
                lst[i][r] += rsum;
                int chunkp = s ^ (prow & 15);
                *(bf16x8*)&p_lds[pbase + prow * 128 + (chunkp << 3)] = pk;
            }

        // ---- O += P V (p rows wave-private; in-wave ordering suffices) ----
#pragma unroll
        for (int kk = 0; kk < 4; kk++) {
            bf16x8 ap[2];
#pragma unroll
            for (int i = 0; i < 2; i++) {
                int prow = i * 16 + s;             // prow & 15 == s
                int chunkr = ((kk << 2) + q) ^ s;
                ap[i] = *(const bf16x8*)&p_lds[pbase + prow * 128 + (chunkr << 3)];
            }
#pragma unroll
            for (int jd = 0; jd < 4; jd++) {
                int d    = jd * 16 + s;
                int vidx = (d * 16 + (((kk << 2) + q) ^ (d & 7))) << 3;
                bf16x8 bv = *(const bf16x8*)&vt_lds[vidx];
                acc_o[0][jd] = MFMA(ap[0], bv, acc_o[0][jd]);
                acc_o[1][jd] = MFMA(ap[1], bv, acc_o[1][jd]);
            }
        }
    }

    // ---- deferred l reduction over the 16 s-lanes (q preserved by xor<16) ----
#pragma unroll
    for (int i = 0; i < 2; i++)
#pragma unroll
        for (int r = 0; r < 4; r++) {
#pragma unroll
            for (int off = 1; off < 16; off <<= 1)
                lst[i][r] += __shfl_xor(lst[i][r], off);
        }

    // ---- epilogue: O / l, merge heads ----
#pragma unroll
    for (int i = 0; i < 2; i++)
#pragma unroll
        for (int jd = 0; jd < 4; jd++)
#pragma unroll
            for (int r = 0; r < 4; r++) {
                int row = qt * 128 + w * 32 + i * 16 + q * 4 + r;
                int col = h * 64 + jd * 16 + s;
                float v = acc_o[i][jd][r] / lst[i][r];
                O[(size_t)(b * 2048 + row) * 1024 + col] = (__bf16)v;
            }
}

// ---------------------------------------------------------------------------
extern "C" void kernel_launch(void* const* d_in, const int* in_sizes, int n_in,
                              void* d_out, int out_size, void* d_ws, size_t ws_size,
                              hipStream_t stream)
{
    const float* hs = (const float*)d_in[0];
    const float* qw = (const float*)d_in[1];
    const float* qb = (const float*)d_in[2];
    const float* kw = (const float*)d_in[3];
    const float* kb = (const float*)d_in[4];
    const float* vw = (const float*)d_in[5];
    const float* vb = (const float*)d_in[6];
    const float* ow = (const float*)d_in[7];
    const float* ob = (const float*)d_in[8];
    float* out = (float*)d_out;

    char* ws = (char*)d_ws;
    const size_t MB = (size_t)1024 * 1024;
    __bf16* Xb  = (__bf16*)(ws);             //  8 MB  [4096,1024]
    __bf16* Wqb = (__bf16*)(ws +  8 * MB);   //  2 MB
    __bf16* Wkb = (__bf16*)(ws + 10 * MB);   //  2 MB
    __bf16* Wvb = (__bf16*)(ws + 12 * MB);   //  2 MB
    __bf16* Wob = (__bf16*)(ws + 14 * MB);   //  2 MB
    __bf16* Qb  = (__bf16*)(ws + 16 * MB);   //  8 MB
    __bf16* Kb  = (__bf16*)(ws + 24 * MB);   //  8 MB
    __bf16* Vtb = (__bf16*)(ws + 32 * MB);   //  8 MB  [32 bh][64 d][2048 s]
    __bf16* Ab  = (__bf16*)(ws + 40 * MB);   //  8 MB

    cvt5_kernel<<<dim3(8192), dim3(256), 0, stream>>>(hs, qw, kw, vw, ow,
                                                      Xb, Wqb, Wkb, Wvb, Wob);

    gemm_qkv_kernel<<<dim3(768), dim3(256), 0, stream>>>(Xb, Wqb, qb, Wkb, kb, Wvb, vb,
                                                         Qb, Kb, Vtb);
    attn_kernel<<<dim3(512), dim3(256), 0, stream>>>(Qb, Kb, Vtb, Ab);
    gemm_o_kernel<<<dim3(512), dim3(256), 0, stream>>>(Ab, Wob, ob, out);
}